// Round 2
// baseline (55.431 us; speedup 1.0000x reference)
//
#include <hip/hip_runtime.h>
#include <hip/hip_cooperative_groups.h>
#include <math.h>

namespace cg = cooperative_groups;

// DTLN part-2: enc matvec -> global LN -> LSTM1 -> LSTM2 -> dense mask -> dec matvec
// Single cooperative kernel, 3 grid syncs. Latency-bound problem (~1.8 MFLOP, 3.4 MB weights).

#define FRAME 1024
#define ENC 256
#define HID 128
#define NBLK 64

__device__ __forceinline__ float wave_reduce(float v) {
#pragma unroll
    for (int o = 32; o > 0; o >>= 1) v += __shfl_down(v, o);
    return v;  // valid on lane 0
}

__device__ __forceinline__ float sigmoidf(float x) { return 1.0f / (1.0f + expf(-x)); }

__global__ __launch_bounds__(256) void k_fused(
    const float* __restrict__ y1, const float* __restrict__ h1_in,
    const float* __restrict__ c1_in, const float* __restrict__ h2_in,
    const float* __restrict__ c2_in, const float* __restrict__ enc_W,
    const float* __restrict__ gamma, const float* __restrict__ beta,
    const float* __restrict__ Wih1, const float* __restrict__ Whh1,
    const float* __restrict__ bih1, const float* __restrict__ bhh1,
    const float* __restrict__ Wih2, const float* __restrict__ Whh2,
    const float* __restrict__ bih2, const float* __restrict__ bhh2,
    const float* __restrict__ dense_W, const float* __restrict__ dense_b,
    const float* __restrict__ dec_W, float* __restrict__ out,
    float* __restrict__ ws)
{
    cg::grid_group grid = cg::this_grid();
    const int t = threadIdx.x, lane = t & 63, wid = t >> 6, bid = blockIdx.x;
    float* enc_g = ws;        // 256
    float* z1    = ws + 256;  // 512
    float* z2    = ws + 768;  // 512

    __shared__ __align__(16) float encn[ENC];
    __shared__ __align__(16) float hA[HID];   // h1_in -> h1
    __shared__ __align__(16) float hB[HID];   // h2_in -> h2
    __shared__ __align__(16) float es[ENC];
    __shared__ float red[8];

    // ---- Stage 1: enc = enc_W @ y1 (256 rows x 1024; 1 row/wave, 16 f/lane) ----
    {
        const int row = bid * 4 + wid;  // 64 blk * 4 waves = 256 rows
        const float4* Wr = reinterpret_cast<const float4*>(enc_W + row * FRAME);
        const float4* Y  = reinterpret_cast<const float4*>(y1);
        float p = 0.f;
#pragma unroll
        for (int k = 0; k < 4; ++k) {
            const float4 a = Wr[k * 64 + lane];
            const float4 b = Y[k * 64 + lane];
            p += a.x * b.x + a.y * b.y + a.z * b.z + a.w * b.w;
        }
        p = wave_reduce(p);
        if (lane == 0) enc_g[row] = p;
    }
    grid.sync();

    // ---- Stage 2: LN (redundant per block) + LSTM1 z1 (512 rows, 2/wave) ----
    {
        const float e = enc_g[t];
        const float s  = wave_reduce(e);
        const float s2 = wave_reduce(e * e);
        if (lane == 0) { red[wid] = s; red[4 + wid] = s2; }
        if (t < HID) hA[t] = h1_in[t];
        __syncthreads();
        const float mean = (red[0] + red[1] + red[2] + red[3]) * (1.f / ENC);
        const float var  = (red[4] + red[5] + red[6] + red[7]) * (1.f / ENC) - mean * mean;
        const float inv  = rsqrtf(var + 1e-7f);
        encn[t] = (e - mean) * inv * gamma[t] + beta[t];
        __syncthreads();
#pragma unroll
        for (int j = 0; j < 2; ++j) {
            const int row = bid * 8 + wid * 2 + j;  // 512 rows
            const float4 a = reinterpret_cast<const float4*>(Wih1 + row * ENC)[lane];
            const float4 b = reinterpret_cast<const float4*>(encn)[lane];
            float p = a.x * b.x + a.y * b.y + a.z * b.z + a.w * b.w;
            const float2 c = reinterpret_cast<const float2*>(Whh1 + row * HID)[lane];
            const float2 d = reinterpret_cast<const float2*>(hA)[lane];
            p += c.x * d.x + c.y * d.y;
            p = wave_reduce(p);
            if (lane == 0) z1[row] = p + bih1[row] + bhh1[row];
        }
    }
    grid.sync();

    // ---- Stage 3: gates1 (redundant) + LSTM2 z2 (512 rows, 2/wave) ----
    {
        if (t < HID) {
            const float i = sigmoidf(z1[t]);
            const float f = sigmoidf(z1[HID + t]);
            const float g = tanhf(z1[2 * HID + t]);
            const float o = sigmoidf(z1[3 * HID + t]);
            const float c = f * c1_in[t] + i * g;
            const float h = o * tanhf(c);
            hA[t] = h;            // h1
            hB[t] = h2_in[t];
            if (bid == 0) { out[FRAME + t] = h; out[FRAME + HID + t] = c; }
        }
        __syncthreads();
#pragma unroll
        for (int j = 0; j < 2; ++j) {
            const int row = bid * 8 + wid * 2 + j;  // 512 rows
            const float2 a = reinterpret_cast<const float2*>(Wih2 + row * HID)[lane];
            const float2 b = reinterpret_cast<const float2*>(hA)[lane];
            const float2 c = reinterpret_cast<const float2*>(Whh2 + row * HID)[lane];
            const float2 d = reinterpret_cast<const float2*>(hB)[lane];
            float p = a.x * b.x + a.y * b.y + c.x * d.x + c.y * d.y;
            p = wave_reduce(p);
            if (lane == 0) z2[row] = p + bih2[row] + bhh2[row];
        }
    }
    grid.sync();

    // ---- Stage 4: gates2 (redundant) + mask/est (redundant) + dec (1024 rows) ----
    {
        if (t < HID) {
            const float i = sigmoidf(z2[t]);
            const float f = sigmoidf(z2[HID + t]);
            const float g = tanhf(z2[2 * HID + t]);
            const float o = sigmoidf(z2[3 * HID + t]);
            const float c = f * c2_in[t] + i * g;
            const float h = o * tanhf(c);
            hB[t] = h;            // h2
            if (bid == 0) { out[FRAME + 2 * HID + t] = h; out[FRAME + 3 * HID + t] = c; }
        }
        __syncthreads();
        {
            // est row t: dot(dense_W[t,:], h2) — LDS reads are wave-uniform (broadcast)
            const float4* wr = reinterpret_cast<const float4*>(dense_W + t * HID);
            const float4* hv = reinterpret_cast<const float4*>(hB);
            float p = 0.f;
#pragma unroll
            for (int k = 0; k < HID / 4; ++k) {
                const float4 a = wr[k];
                const float4 b = hv[k];
                p += a.x * b.x + a.y * b.y + a.z * b.z + a.w * b.w;
            }
            const float m = sigmoidf(p + dense_b[t]);
            es[t] = m * enc_g[t];
        }
        __syncthreads();
#pragma unroll
        for (int j = 0; j < 4; ++j) {
            const int row = bid * 16 + wid * 4 + j;  // 1024 rows
            const float4 a = reinterpret_cast<const float4*>(dec_W + row * ENC)[lane];
            const float4 b = reinterpret_cast<const float4*>(es)[lane];
            float p = a.x * b.x + a.y * b.y + a.z * b.z + a.w * b.w;
            p = wave_reduce(p);
            if (lane == 0) out[row] = p;
        }
    }
}

extern "C" void kernel_launch(void* const* d_in, const int* in_sizes, int n_in,
                              void* d_out, int out_size, void* d_ws, size_t ws_size,
                              hipStream_t stream) {
    const float* y1      = (const float*)d_in[0];
    const float* h1_in   = (const float*)d_in[1];
    const float* c1_in   = (const float*)d_in[2];
    const float* h2_in   = (const float*)d_in[3];
    const float* c2_in   = (const float*)d_in[4];
    const float* enc_W   = (const float*)d_in[5];
    const float* gamma   = (const float*)d_in[6];
    const float* beta    = (const float*)d_in[7];
    const float* Wih1    = (const float*)d_in[8];
    const float* Whh1    = (const float*)d_in[9];
    const float* bih1    = (const float*)d_in[10];
    const float* bhh1    = (const float*)d_in[11];
    const float* Wih2    = (const float*)d_in[12];
    const float* Whh2    = (const float*)d_in[13];
    const float* bih2    = (const float*)d_in[14];
    const float* bhh2    = (const float*)d_in[15];
    const float* dense_W = (const float*)d_in[16];
    const float* dense_b = (const float*)d_in[17];
    const float* dec_W   = (const float*)d_in[18];

    float* out = (float*)d_out;
    float* ws  = (float*)d_ws;

    void* args[] = {
        (void*)&y1, (void*)&h1_in, (void*)&c1_in, (void*)&h2_in, (void*)&c2_in,
        (void*)&enc_W, (void*)&gamma, (void*)&beta,
        (void*)&Wih1, (void*)&Whh1, (void*)&bih1, (void*)&bhh1,
        (void*)&Wih2, (void*)&Whh2, (void*)&bih2, (void*)&bhh2,
        (void*)&dense_W, (void*)&dense_b, (void*)&dec_W,
        (void*)&out, (void*)&ws
    };
    hipLaunchCooperativeKernel((void*)k_fused, dim3(NBLK), dim3(256), args, 0, stream);
}